// Round 4
// baseline (2818.950 us; speedup 1.0000x reference)
//
#include <hip/hip_runtime.h>

typedef unsigned int u32;
typedef unsigned short u16;
typedef __attribute__((ext_vector_type(8))) short bf16x8;   // 8 bf16 = 4 VGPRs (MFMA A/B frag)
typedef __attribute__((ext_vector_type(4))) float f32x4;    // MFMA C/D frag

#define T_STEPS 512
#define NOUT_H  16777216ull   // T*B*H
// workspace byte offsets
#define WS_FLAGS  256ull                       // 256 u32 flags (per producer-wave)
#define WS_BIAS   8192ull                      // f32[2048]
#define WS_HBUF0  16384ull                     // 64KB (swizzled h, parity 0)
#define WS_HBUF1  81920ull                     // 64KB (parity 1)
#define WS_WXS    147456ull                    // 2MB swizzled Wx (bf16)
#define WS_WHS    2244608ull                   // 2MB swizzled Wh (bf16)
#define WS_XC     4341760ull                   // 32MB X as bf16
#define WS_XW     37896192ull                  // XW: 268MB f32 or 134MB bf16

__device__ __forceinline__ u16 f2bf(float f) {
  u32 u = __builtin_bit_cast(u32, f);
  u32 r = (u + 0x7fffu + ((u >> 16) & 1u)) >> 16;
  return (u16)r;
}
__device__ __forceinline__ float bf2f(u16 h) {
  u32 u = ((u32)h) << 16;
  return __builtin_bit_cast(float, u);
}
__device__ __forceinline__ float sigf(float x) {
  return __builtin_amdgcn_rcpf(1.0f + __expf(-x));
}
__device__ __forceinline__ float tanh_fast(float x) {
  float xc = fminf(15.0f, fmaxf(-15.0f, x));
  float e = __expf(2.0f * xc);
  return (e - 1.0f) * __builtin_amdgcn_rcpf(e + 1.0f);
}

// ---------------- K0: dtype detect + zero flags/hbufs ----------------
__global__ void k_detect(const u32* __restrict__ x, u32* __restrict__ ws) {
  __shared__ int cnt;
  if (threadIdx.x == 0) cnt = 0;
  __syncthreads();
  int good = 0;
  for (int i = 0; i < 4; ++i) {
    u32 v = x[threadIdx.x * 4 + i];
    u32 e = (v >> 7) & 0xff;          // low 16 bits interpreted as bf16: exponent field
    good += (e >= 100 && e <= 140) ? 1 : 0;
  }
  atomicAdd(&cnt, good);
  __syncthreads();
  if (threadIdx.x == 0) ws[0] = (cnt >= 512) ? 1u : 0u;  // 1 = bf16 inputs, 0 = f32 inputs
  u32* flags = ws + WS_FLAGS / 4;
  for (int i = threadIdx.x; i < 1024; i += 256) flags[i] = 0;
  u32* hb = ws + WS_HBUF0 / 4;
  for (int i = threadIdx.x; i < (131072 / 4); i += 256) hb[i] = 0;
}

// ---------------- K1: X f32 -> bf16 (no-op in bf16 mode) ----------------
__global__ void k_convx(const u32* __restrict__ ws, const void* __restrict__ xin,
                        u16* __restrict__ xc) {
  if (ws[0]) return;  // bf16 mode: K3 reads input directly
  int idx = blockIdx.x * 256 + threadIdx.x;  // 4 elements each, 16777216 total
  float4 f = ((const float4*)xin)[idx];
  ushort4 o;
  o.x = f2bf(f.x); o.y = f2bf(f.y); o.z = f2bf(f.z); o.w = f2bf(f.w);
  ((ushort4*)xc)[idx] = o;
}

// ---------------- K2: swizzle W into MFMA-fragment-linear chunks + bias ----------------
__global__ void k_prepw(u32* __restrict__ ws,
                        const void* Wf, const void* Wi, const void* Wg, const void* Wo,
                        const void* bfp, const void* bip, const void* bgp, const void* bop) {
  u32 mode = ws[0];
  const void* Wp[4] = {Wf, Wi, Wg, Wo};
  int tid = blockIdx.x * 256 + threadIdx.x;   // 262144 threads
  u16* wxs = (u16*)((char*)ws + WS_WXS);
  u16* whs = (u16*)((char*)ws + WS_WHS);
  int c, iswh;
  if (tid < 131072) { c = tid; iswh = 0; } else { c = tid - 131072; iswh = 1; }
  int n = c & 15, q = (c >> 4) & 3, ks = (c >> 6) & 15;
  int g, j, krow0;
  if (!iswh) {                       // Wx chunks: [ntg(128)][ks][q][n]
    int ntg = c >> 10;
    int col = ntg * 16 + n; g = col >> 9; j = col & 511; krow0 = 0;
  } else {                           // Wh chunks: [w(64)][nt(2)][ks][q][n], col = g*512 + w*8 + jj
    int nt = (c >> 10) & 1, w = c >> 11;
    int cl = nt * 16 + n; g = cl >> 3; j = w * 8 + (cl & 7); krow0 = 512;
  }
  int kbase = krow0 + ks * 32 + q * 8;
  u16 vals[8];
  if (mode) {
    const u16* Ws = (const u16*)Wp[g];
    for (int jj = 0; jj < 8; ++jj) vals[jj] = Ws[(size_t)(kbase + jj) * 512 + j];
  } else {
    const float* Ws = (const float*)Wp[g];
    for (int jj = 0; jj < 8; ++jj) vals[jj] = f2bf(Ws[(size_t)(kbase + jj) * 512 + j]);
  }
  uint4 pk;
  pk.x = (u32)vals[0] | ((u32)vals[1] << 16);
  pk.y = (u32)vals[2] | ((u32)vals[3] << 16);
  pk.z = (u32)vals[4] | ((u32)vals[5] << 16);
  pk.w = (u32)vals[6] | ((u32)vals[7] << 16);
  ((uint4*)(iswh ? whs : wxs))[c] = pk;
  if (tid < 2048) {
    const void* bp[4] = {bfp, bip, bgp, bop};
    int bg = tid >> 9, bj = tid & 511;
    float* bias = (float*)((char*)ws + WS_BIAS);
    bias[tid] = mode ? bf2f(((const u16*)bp[bg])[bj]) : ((const float*)bp[bg])[bj];
  }
}

// ---------------- K3: XW = X @ Wx + b, stored in K4 C-frag-linear layout ----------------
__global__ __launch_bounds__(256) void k_xw(u32* __restrict__ ws, const void* __restrict__ xorig,
                                            int xwf32) {
  u32 mode = ws[0];
  const u16* xc = mode ? (const u16*)xorig : (const u16*)((char*)ws + WS_XC);
  const u16* wxs = (const u16*)((char*)ws + WS_WXS);
  const float* bias = (const float*)((char*)ws + WS_BIAS);
  char* xwp = (char*)ws + WS_XW;
  int v = threadIdx.x >> 6, lane = threadIdx.x & 63, q = lane >> 4, n = lane & 15;
  int mg = blockIdx.x >> 4, ng = blockIdx.x & 15;
  f32x4 acc[4][2] = {};
  for (int ks = 0; ks < 16; ++ks) {
    bf16x8 a[4];
#pragma unroll
    for (int mt = 0; mt < 4; ++mt)
      a[mt] = *(const bf16x8*)(xc + ((size_t)(mg * 64 + mt * 16 + n) * 512 + ks * 32 + q * 8));
#pragma unroll
    for (int jb = 0; jb < 2; ++jb) {
      int ntg = ng * 8 + v * 2 + jb;
      bf16x8 b = *(const bf16x8*)(wxs + ((size_t)(ntg * 16 + ks) * 64 + lane) * 8);
#pragma unroll
      for (int mt = 0; mt < 4; ++mt)
        acc[mt][jb] = __builtin_amdgcn_mfma_f32_16x16x32_bf16(a[mt], b, acc[mt][jb], 0, 0, 0);
    }
  }
#pragma unroll
  for (int jb = 0; jb < 2; ++jb) {
    int ntg = ng * 8 + v * 2 + jb;
    int col = ntg * 16 + n;
    float bv = bias[col];
    int g = col >> 9, j = col & 511;
    int w = j >> 3, cl = g * 8 + (j & 7);
    int nt4 = cl >> 4, n4 = cl & 15;
#pragma unroll
    for (int mt = 0; mt < 4; ++mt) {
      // XWswz layout: [t][v4(4)][w(64)][nt(2)][lane(64)][r(4)] ; v4 = mt, lane = q*16+n4
      size_t base = ((((size_t)mg * 4 + mt) * 64 + w) * 2 + nt4) * 64 + q * 16 + n4;
      f32x4 vec = acc[mt][jb];
      vec[0] += bv; vec[1] += bv; vec[2] += bv; vec[3] += bv;
      if (xwf32) {
        ((f32x4*)xwp)[base] = vec;
      } else {
        ushort4 o;
        o.x = f2bf(vec[0]); o.y = f2bf(vec[1]); o.z = f2bf(vec[2]); o.w = f2bf(vec[3]);
        ((ushort4*)xwp)[base] = o;
      }
    }
  }
}

// ---------------- K4: persistent recurrent kernel ----------------
// 64 WGs x 256. WG w owns h-cols [w*8,w*8+8). Wave v owns batch rows [v*16,v*16+16).
// Wh in REGISTERS (bfr[2][16], 128 VGPR; 1 wave/SIMD -> 512 budget). No LDS in loop.
// h double-buffered in global (A-frag chunk layout); coherent sc0sc1 stores/loads;
// per-wave monotonic flags, wave-v polls only its 64 wave-v producers.
// Gate exchange via shfl_xor(8); publish = 2 coherent u16 stores/lane.
// Tail order: publish -> vmcnt(0) -> flag -> XW(t+1) prefetch + out stores (drain in next poll).
__global__ __launch_bounds__(256, 1) void k_rec(u32* __restrict__ ws, void* __restrict__ out,
                                                int xwf32) {
  u32 mode = ws[0];
  u32* flags = ws + WS_FLAGS / 4;
  const u16* whs = (const u16*)((char*)ws + WS_WHS);
  char* hb0 = (char*)ws + WS_HBUF0;
  char* hb1 = (char*)ws + WS_HBUF1;
  const char* xwp = (const char*)ws + WS_XW;
  int w = blockIdx.x, tid = threadIdx.x, v = tid >> 6, lane = tid & 63;
  int q = lane >> 4, n = lane & 15;
  int hi = (n >> 3) & 1;              // lane half within 16-group
  int r0 = hi ? 2 : 0;
  int jj = n & 7;

  // Wh fragments -> registers (2 ntiles x 16 ksteps x 16B = 128 VGPRs)
  bf16x8 bfr[2][16];
#pragma unroll
  for (int nt = 0; nt < 2; ++nt)
#pragma unroll
    for (int ks = 0; ks < 16; ++ks)
      bfr[nt][ks] = *(const bf16x8*)(whs + ((size_t)w * 2048 + nt * 1024 + ks * 64 + lane) * 8);

  float creg[2] = {0.f, 0.f};         // c-state for items (rr = q*4 + r0 + it, jj)
  u32* fp = flags + lane * 4 + v;     // lane polls producer WG 'lane', wave v

  // XW(0) preload
  f32x4 xw0, xw1;
  {
    size_t b0 = ((((size_t)0 * 4 + v) * 64 + w) * 2 + 0) * 64 + lane;
    if (xwf32) {
      xw0 = ((const f32x4*)xwp)[b0];
      xw1 = ((const f32x4*)xwp)[b0 + 64];
    } else {
      ushort4 a0 = ((const ushort4*)xwp)[b0];
      ushort4 a1 = ((const ushort4*)xwp)[b0 + 64];
      xw0[0] = bf2f(a0.x); xw0[1] = bf2f(a0.y); xw0[2] = bf2f(a0.z); xw0[3] = bf2f(a0.w);
      xw1[0] = bf2f(a1.x); xw1[1] = bf2f(a1.y); xw1[2] = bf2f(a1.z); xw1[3] = bf2f(a1.w);
    }
  }

  for (int t = 0; t < T_STEPS; ++t) {
    // ---- poll: the 64 wave-v producers published step t (tight spin) ----
    {
      u32 need = (u32)t;
      while (true) {
        u32 f;
        asm volatile("global_load_dword %0, %1, off sc0 sc1\n\ts_waitcnt vmcnt(0)"
                     : "=&v"(f) : "v"(fp) : "memory");
        if (__all((int)(f >= need))) break;
      }
    }
    const char* hcur = (t & 1) ? hb1 : hb0;
    char* hnxt = (t & 1) ? hb0 : hb1;

    // ---- coherent h loads: 16 x 16B per lane, single asm block ending in vmcnt(0) ----
    uint4 ha[16];
    {
      const char* b0 = hcur + (size_t)v * 16384 + (size_t)lane * 16;
      const char* b4 = b0 + 4096;
      const char* b8 = b0 + 8192;
      const char* b12 = b0 + 12288;
      asm volatile(
          "global_load_dwordx4 %0, %16, off sc0 sc1\n\t"
          "global_load_dwordx4 %1, %16, off offset:1024 sc0 sc1\n\t"
          "global_load_dwordx4 %2, %16, off offset:2048 sc0 sc1\n\t"
          "global_load_dwordx4 %3, %16, off offset:3072 sc0 sc1\n\t"
          "global_load_dwordx4 %4, %17, off sc0 sc1\n\t"
          "global_load_dwordx4 %5, %17, off offset:1024 sc0 sc1\n\t"
          "global_load_dwordx4 %6, %17, off offset:2048 sc0 sc1\n\t"
          "global_load_dwordx4 %7, %17, off offset:3072 sc0 sc1\n\t"
          "global_load_dwordx4 %8, %18, off sc0 sc1\n\t"
          "global_load_dwordx4 %9, %18, off offset:1024 sc0 sc1\n\t"
          "global_load_dwordx4 %10, %18, off offset:2048 sc0 sc1\n\t"
          "global_load_dwordx4 %11, %18, off offset:3072 sc0 sc1\n\t"
          "global_load_dwordx4 %12, %19, off sc0 sc1\n\t"
          "global_load_dwordx4 %13, %19, off offset:1024 sc0 sc1\n\t"
          "global_load_dwordx4 %14, %19, off offset:2048 sc0 sc1\n\t"
          "global_load_dwordx4 %15, %19, off offset:3072 sc0 sc1\n\t"
          "s_waitcnt vmcnt(0)"
          : "=&v"(ha[0]), "=&v"(ha[1]), "=&v"(ha[2]), "=&v"(ha[3]),
            "=&v"(ha[4]), "=&v"(ha[5]), "=&v"(ha[6]), "=&v"(ha[7]),
            "=&v"(ha[8]), "=&v"(ha[9]), "=&v"(ha[10]), "=&v"(ha[11]),
            "=&v"(ha[12]), "=&v"(ha[13]), "=&v"(ha[14]), "=&v"(ha[15])
          : "v"(b0), "v"(b4), "v"(b8), "v"(b12)
          : "memory");
    }

    // ---- MFMA: 4 chains of 8 (k-split), B from registers ----
    f32x4 a0a = xw0, a1a = xw1;
    f32x4 a0b = {0.f, 0.f, 0.f, 0.f}, a1b = {0.f, 0.f, 0.f, 0.f};
#pragma unroll
    for (int ks = 0; ks < 8; ++ks) {
      bf16x8 aA = __builtin_bit_cast(bf16x8, ha[ks]);
      bf16x8 aB = __builtin_bit_cast(bf16x8, ha[8 + ks]);
      a0a = __builtin_amdgcn_mfma_f32_16x16x32_bf16(aA, bfr[0][ks], a0a, 0, 0, 0);
      a1a = __builtin_amdgcn_mfma_f32_16x16x32_bf16(aA, bfr[1][ks], a1a, 0, 0, 0);
      a0b = __builtin_amdgcn_mfma_f32_16x16x32_bf16(aB, bfr[0][8 + ks], a0b, 0, 0, 0);
      a1b = __builtin_amdgcn_mfma_f32_16x16x32_bf16(aB, bfr[1][8 + ks], a1b, 0, 0, 0);
    }
    f32x4 acc0 = a0a + a0b, acc1 = a1a + a1b;

    // ---- gate exchange via shfl_xor(8): lanes n<8 hold F,G; n>=8 hold I,O ----
    // t0x[it] : lo lane receives partner acc0[it] (=I, r=it); hi receives partner acc0[2+it] (=F, r=2+it)
    float t00 = __shfl_xor(hi ? acc0[0] : acc0[2], 8, 64);
    float t01 = __shfl_xor(hi ? acc0[1] : acc0[3], 8, 64);
    float t20 = __shfl_xor(hi ? acc1[0] : acc1[2], 8, 64);
    float t21 = __shfl_xor(hi ? acc1[1] : acc1[3], 8, 64);

    float hnew_s[2], cnew_s[2];
    u32 h16_s[2];
#pragma unroll
    for (int it = 0; it < 2; ++it) {
      int r = r0 + it;
      float tx0 = it ? t01 : t00;
      float tx2 = it ? t21 : t20;
      float zf = hi ? tx0 : acc0[it];
      float zi = hi ? acc0[r] : tx0;
      float zg = hi ? tx2 : acc1[it];
      float zo = hi ? acc1[r] : tx2;
      float fg = sigf(zf), ig = sigf(zi), gg = tanh_fast(zg), og = sigf(zo);
      float cnew = fg * creg[it] + ig * gg;
      float hnew = og * tanh_fast(cnew);
      creg[it] = cnew;
      hnew_s[it] = hnew; cnew_s[it] = cnew;
      h16_s[it] = (u32)f2bf(hnew);
    }

    // ---- publish: 2 coherent u16 stores (chunk rr=q*4+r0+{0,1}, byte +16 apart) ----
    {
      size_t ci0 = ((((size_t)v * 16 + (w >> 2)) * 4 + (w & 3)) * 16 + (q * 4 + r0));
      char* dst = hnxt + ci0 * 16 + jj * 2;
      asm volatile(
          "global_store_short %0, %1, off sc0 sc1\n\t"
          "global_store_short %0, %2, off offset:16 sc0 sc1"
          :: "v"(dst), "v"(h16_s[0]), "v"(h16_s[1]) : "memory");
    }
    asm volatile("s_waitcnt vmcnt(0)" ::: "memory");
    if (lane == 0) {
      u32 tag = (u32)(t + 1);
      u32* fdst = flags + (w * 4 + v);
      asm volatile("global_store_dword %0, %1, off sc0 sc1" :: "v"(fdst), "v"(tag) : "memory");
    }

    // ---- shadow work: XW(t+1) prefetch + out stores (drain during next poll) ----
    {
      int tn = (t + 1 < T_STEPS) ? t + 1 : t;
      size_t b0 = ((((size_t)tn * 4 + v) * 64 + w) * 2 + 0) * 64 + lane;
      if (xwf32) {
        xw0 = ((const f32x4*)xwp)[b0];
        xw1 = ((const f32x4*)xwp)[b0 + 64];
      } else {
        ushort4 a0 = ((const ushort4*)xwp)[b0];
        ushort4 a1 = ((const ushort4*)xwp)[b0 + 64];
        xw0[0] = bf2f(a0.x); xw0[1] = bf2f(a0.y); xw0[2] = bf2f(a0.z); xw0[3] = bf2f(a0.w);
        xw1[0] = bf2f(a1.x); xw1[1] = bf2f(a1.y); xw1[2] = bf2f(a1.z); xw1[3] = bf2f(a1.w);
      }
    }
#pragma unroll
    for (int it = 0; it < 2; ++it) {
      int b = v * 16 + q * 4 + r0 + it;
      size_t oi = ((size_t)t * 64 + b) * 512 + w * 8 + jj;
      if (mode) ((u16*)out)[oi] = (u16)h16_s[it]; else ((float*)out)[oi] = hnew_s[it];
      if (t == T_STEPS - 1) {
        size_t hx = NOUT_H + (size_t)b * 512 + w * 8 + jj;
        if (mode) { ((u16*)out)[hx] = (u16)h16_s[it]; ((u16*)out)[hx + 32768] = f2bf(cnew_s[it]); }
        else      { ((float*)out)[hx] = hnew_s[it]; ((float*)out)[hx + 32768] = cnew_s[it]; }
      }
    }
  }
}

extern "C" void kernel_launch(void* const* d_in, const int* in_sizes, int n_in,
                              void* d_out, int out_size, void* d_ws, size_t ws_size,
                              hipStream_t stream) {
  const void* X = d_in[0];
  u32* ws = (u32*)d_ws;
  int xwf32 = (ws_size >= (size_t)(WS_XW + 268435456ull + 1024ull)) ? 1 : 0;

  k_detect<<<1, 256, 0, stream>>>((const u32*)X, ws);
  k_convx<<<16384, 256, 0, stream>>>(ws, X, (u16*)((char*)d_ws + WS_XC));
  k_prepw<<<1024, 256, 0, stream>>>(ws, d_in[1], d_in[3], d_in[5], d_in[7],
                                    d_in[2], d_in[4], d_in[6], d_in[8]);
  k_xw<<<8192, 256, 0, stream>>>(ws, X, xwf32);
  k_rec<<<64, 256, 0, stream>>>(ws, d_out, xwf32);
}

// Round 5
// 2741.912 us; speedup vs baseline: 1.0281x; 1.0281x over previous
//
#include <hip/hip_runtime.h>

typedef unsigned int u32;
typedef unsigned short u16;
typedef __attribute__((ext_vector_type(8))) short bf16x8;   // 8 bf16 = 4 VGPRs (MFMA A/B frag)
typedef __attribute__((ext_vector_type(4))) float f32x4;    // MFMA C/D frag

#define T_STEPS 512
#define NOUT_H  16777216ull   // T*B*H
// workspace byte offsets
#define WS_FLAGS  256ull                       // 256 u32 flags (per producer-wave)
#define WS_BIAS   8192ull                      // f32[2048]
#define WS_HBUF0  16384ull                     // 64KB (swizzled h, parity 0)
#define WS_HBUF1  81920ull                     // 64KB (parity 1)
#define WS_WXS    147456ull                    // 2MB swizzled Wx (bf16)
#define WS_WHS    2244608ull                   // 2MB swizzled Wh (bf16)
#define WS_XC     4341760ull                   // 32MB X as bf16
#define WS_XW     37896192ull                  // XW: 268MB f32 or 134MB bf16

__device__ __forceinline__ u16 f2bf(float f) {
  u32 u = __builtin_bit_cast(u32, f);
  u32 r = (u + 0x7fffu + ((u >> 16) & 1u)) >> 16;
  return (u16)r;
}
__device__ __forceinline__ float bf2f(u16 h) {
  u32 u = ((u32)h) << 16;
  return __builtin_bit_cast(float, u);
}
__device__ __forceinline__ float sigf(float x) {
  return __builtin_amdgcn_rcpf(1.0f + __expf(-x));
}
__device__ __forceinline__ float tanh_fast(float x) {
  float xc = fminf(15.0f, fmaxf(-15.0f, x));
  float e = __expf(2.0f * xc);
  return (e - 1.0f) * __builtin_amdgcn_rcpf(e + 1.0f);
}

// ---------------- K0: dtype detect + zero flags/hbufs ----------------
__global__ void k_detect(const u32* __restrict__ x, u32* __restrict__ ws) {
  __shared__ int cnt;
  if (threadIdx.x == 0) cnt = 0;
  __syncthreads();
  int good = 0;
  for (int i = 0; i < 4; ++i) {
    u32 v = x[threadIdx.x * 4 + i];
    u32 e = (v >> 7) & 0xff;          // low 16 bits interpreted as bf16: exponent field
    good += (e >= 100 && e <= 140) ? 1 : 0;
  }
  atomicAdd(&cnt, good);
  __syncthreads();
  if (threadIdx.x == 0) ws[0] = (cnt >= 512) ? 1u : 0u;  // 1 = bf16 inputs, 0 = f32 inputs
  u32* flags = ws + WS_FLAGS / 4;
  for (int i = threadIdx.x; i < 1024; i += 256) flags[i] = 0;
  u32* hb = ws + WS_HBUF0 / 4;
  for (int i = threadIdx.x; i < (131072 / 4); i += 256) hb[i] = 0;
}

// ---------------- K1: X f32 -> bf16 (no-op in bf16 mode) ----------------
__global__ void k_convx(const u32* __restrict__ ws, const void* __restrict__ xin,
                        u16* __restrict__ xc) {
  if (ws[0]) return;  // bf16 mode: K3 reads input directly
  int idx = blockIdx.x * 256 + threadIdx.x;  // 4 elements each, 16777216 total
  float4 f = ((const float4*)xin)[idx];
  ushort4 o;
  o.x = f2bf(f.x); o.y = f2bf(f.y); o.z = f2bf(f.z); o.w = f2bf(f.w);
  ((ushort4*)xc)[idx] = o;
}

// ---------------- K2: swizzle W into MFMA-fragment-linear chunks + bias ----------------
__global__ void k_prepw(u32* __restrict__ ws,
                        const void* Wf, const void* Wi, const void* Wg, const void* Wo,
                        const void* bfp, const void* bip, const void* bgp, const void* bop) {
  u32 mode = ws[0];
  const void* Wp[4] = {Wf, Wi, Wg, Wo};
  int tid = blockIdx.x * 256 + threadIdx.x;   // 262144 threads
  u16* wxs = (u16*)((char*)ws + WS_WXS);
  u16* whs = (u16*)((char*)ws + WS_WHS);
  int c, iswh;
  if (tid < 131072) { c = tid; iswh = 0; } else { c = tid - 131072; iswh = 1; }
  int n = c & 15, q = (c >> 4) & 3, ks = (c >> 6) & 15;
  int g, j, krow0;
  if (!iswh) {                       // Wx chunks: [ntg(128)][ks][q][n]
    int ntg = c >> 10;
    int col = ntg * 16 + n; g = col >> 9; j = col & 511; krow0 = 0;
  } else {                           // Wh chunks: [w(64)][nt(2)][ks][q][n], col = g*512 + w*8 + jj
    int nt = (c >> 10) & 1, w = c >> 11;
    int cl = nt * 16 + n; g = cl >> 3; j = w * 8 + (cl & 7); krow0 = 512;
  }
  int kbase = krow0 + ks * 32 + q * 8;
  u16 vals[8];
  if (mode) {
    const u16* Ws = (const u16*)Wp[g];
    for (int jj = 0; jj < 8; ++jj) vals[jj] = Ws[(size_t)(kbase + jj) * 512 + j];
  } else {
    const float* Ws = (const float*)Wp[g];
    for (int jj = 0; jj < 8; ++jj) vals[jj] = f2bf(Ws[(size_t)(kbase + jj) * 512 + j]);
  }
  uint4 pk;
  pk.x = (u32)vals[0] | ((u32)vals[1] << 16);
  pk.y = (u32)vals[2] | ((u32)vals[3] << 16);
  pk.z = (u32)vals[4] | ((u32)vals[5] << 16);
  pk.w = (u32)vals[6] | ((u32)vals[7] << 16);
  ((uint4*)(iswh ? whs : wxs))[c] = pk;
  if (tid < 2048) {
    const void* bp[4] = {bfp, bip, bgp, bop};
    int bg = tid >> 9, bj = tid & 511;
    float* bias = (float*)((char*)ws + WS_BIAS);
    bias[tid] = mode ? bf2f(((const u16*)bp[bg])[bj]) : ((const float*)bp[bg])[bj];
  }
}

// ---------------- K3: XW = X @ Wx + b, stored in K4 C-frag-linear layout ----------------
__global__ __launch_bounds__(256) void k_xw(u32* __restrict__ ws, const void* __restrict__ xorig,
                                            int xwf32) {
  u32 mode = ws[0];
  const u16* xc = mode ? (const u16*)xorig : (const u16*)((char*)ws + WS_XC);
  const u16* wxs = (const u16*)((char*)ws + WS_WXS);
  const float* bias = (const float*)((char*)ws + WS_BIAS);
  char* xwp = (char*)ws + WS_XW;
  int v = threadIdx.x >> 6, lane = threadIdx.x & 63, q = lane >> 4, n = lane & 15;
  int mg = blockIdx.x >> 4, ng = blockIdx.x & 15;
  f32x4 acc[4][2] = {};
  for (int ks = 0; ks < 16; ++ks) {
    bf16x8 a[4];
#pragma unroll
    for (int mt = 0; mt < 4; ++mt)
      a[mt] = *(const bf16x8*)(xc + ((size_t)(mg * 64 + mt * 16 + n) * 512 + ks * 32 + q * 8));
#pragma unroll
    for (int jb = 0; jb < 2; ++jb) {
      int ntg = ng * 8 + v * 2 + jb;
      bf16x8 b = *(const bf16x8*)(wxs + ((size_t)(ntg * 16 + ks) * 64 + lane) * 8);
#pragma unroll
      for (int mt = 0; mt < 4; ++mt)
        acc[mt][jb] = __builtin_amdgcn_mfma_f32_16x16x32_bf16(a[mt], b, acc[mt][jb], 0, 0, 0);
    }
  }
#pragma unroll
  for (int jb = 0; jb < 2; ++jb) {
    int ntg = ng * 8 + v * 2 + jb;
    int col = ntg * 16 + n;
    float bv = bias[col];
    int g = col >> 9, j = col & 511;
    int w = j >> 3, cl = g * 8 + (j & 7);
    int nt4 = cl >> 4, n4 = cl & 15;
#pragma unroll
    for (int mt = 0; mt < 4; ++mt) {
      // XWswz layout: [t][v4(4)][w(64)][nt(2)][lane(64)][r(4)] ; v4 = mt, lane = q*16+n4
      size_t base = ((((size_t)mg * 4 + mt) * 64 + w) * 2 + nt4) * 64 + q * 16 + n4;
      f32x4 vec = acc[mt][jb];
      vec[0] += bv; vec[1] += bv; vec[2] += bv; vec[3] += bv;
      if (xwf32) {
        ((f32x4*)xwp)[base] = vec;
      } else {
        ushort4 o;
        o.x = f2bf(vec[0]); o.y = f2bf(vec[1]); o.z = f2bf(vec[2]); o.w = f2bf(vec[3]);
        ((ushort4*)xwp)[base] = o;
      }
    }
  }
}

// ---------------- K4: persistent recurrent kernel ----------------
// 64 WGs x 256. WG w owns h-cols [w*8,w*8+8). Wave v owns batch rows [v*16,v*16+16).
// Wh in registers/AGPRs (bfr[2][16]). No LDS in loop. h double-buffered in global
// (A-frag chunk layout); coherent sc0sc1 accesses; per-wave monotonic flags; wave-v
// polls only its 64 wave-v producers. Gate exchange via shfl_xor(8). Publish = paired
// shfl_xor(1) -> full-DWORD coherent stores (no sub-dword RMW at LLC). "memory"
// clobber ONLY on the post-publish drain; elsewhere rely on asm-volatile ordering.
__global__ __launch_bounds__(256, 1) void k_rec(u32* __restrict__ ws, void* __restrict__ out,
                                                int xwf32) {
  u32 mode = ws[0];
  u32* flags = ws + WS_FLAGS / 4;
  const u16* whs = (const u16*)((char*)ws + WS_WHS);
  char* hb0 = (char*)ws + WS_HBUF0;
  char* hb1 = (char*)ws + WS_HBUF1;
  const char* xwp = (const char*)ws + WS_XW;
  int w = blockIdx.x, tid = threadIdx.x, v = tid >> 6, lane = tid & 63;
  int q = lane >> 4, n = lane & 15;
  int hi = (n >> 3) & 1;              // lane half within 16-group
  int r0 = hi ? 2 : 0;
  int jj = n & 7;

  // Wh fragments -> registers (2 ntiles x 16 ksteps x 16B = 128 regs, AGPR-eligible)
  bf16x8 bfr[2][16];
#pragma unroll
  for (int nt = 0; nt < 2; ++nt)
#pragma unroll
    for (int ks = 0; ks < 16; ++ks)
      bfr[nt][ks] = *(const bf16x8*)(whs + ((size_t)w * 2048 + nt * 1024 + ks * 64 + lane) * 8);

  float creg[2] = {0.f, 0.f};         // c-state for items (rr = q*4 + r0 + it, jj)
  u32* fp = flags + lane * 4 + v;     // lane polls producer WG 'lane', wave v

  // XW(0) preload
  f32x4 xw0, xw1;
  {
    size_t b0 = ((((size_t)0 * 4 + v) * 64 + w) * 2 + 0) * 64 + lane;
    if (xwf32) {
      xw0 = ((const f32x4*)xwp)[b0];
      xw1 = ((const f32x4*)xwp)[b0 + 64];
    } else {
      ushort4 a0 = ((const ushort4*)xwp)[b0];
      ushort4 a1 = ((const ushort4*)xwp)[b0 + 64];
      xw0[0] = bf2f(a0.x); xw0[1] = bf2f(a0.y); xw0[2] = bf2f(a0.z); xw0[3] = bf2f(a0.w);
      xw1[0] = bf2f(a1.x); xw1[1] = bf2f(a1.y); xw1[2] = bf2f(a1.z); xw1[3] = bf2f(a1.w);
    }
  }

  for (int t = 0; t < T_STEPS; ++t) {
    // ---- poll: the 64 wave-v producers published step t (tight spin, no clobber) ----
    {
      u32 need = (u32)t;
      while (true) {
        u32 f;
        asm volatile("global_load_dword %0, %1, off sc0 sc1\n\ts_waitcnt vmcnt(0)"
                     : "=&v"(f) : "v"(fp));
        if (__all((int)(f >= need))) break;
      }
    }
    const char* hcur = (t & 1) ? hb1 : hb0;
    char* hnxt = (t & 1) ? hb0 : hb1;

    // ---- coherent h loads: 16 x 16B per lane, single asm block, no clobber ----
    uint4 ha[16];
    {
      const char* b0 = hcur + (size_t)v * 16384 + (size_t)lane * 16;
      const char* b4 = b0 + 4096;
      const char* b8 = b0 + 8192;
      const char* b12 = b0 + 12288;
      asm volatile(
          "global_load_dwordx4 %0, %16, off sc0 sc1\n\t"
          "global_load_dwordx4 %1, %16, off offset:1024 sc0 sc1\n\t"
          "global_load_dwordx4 %2, %16, off offset:2048 sc0 sc1\n\t"
          "global_load_dwordx4 %3, %16, off offset:3072 sc0 sc1\n\t"
          "global_load_dwordx4 %4, %17, off sc0 sc1\n\t"
          "global_load_dwordx4 %5, %17, off offset:1024 sc0 sc1\n\t"
          "global_load_dwordx4 %6, %17, off offset:2048 sc0 sc1\n\t"
          "global_load_dwordx4 %7, %17, off offset:3072 sc0 sc1\n\t"
          "global_load_dwordx4 %8, %18, off sc0 sc1\n\t"
          "global_load_dwordx4 %9, %18, off offset:1024 sc0 sc1\n\t"
          "global_load_dwordx4 %10, %18, off offset:2048 sc0 sc1\n\t"
          "global_load_dwordx4 %11, %18, off offset:3072 sc0 sc1\n\t"
          "global_load_dwordx4 %12, %19, off sc0 sc1\n\t"
          "global_load_dwordx4 %13, %19, off offset:1024 sc0 sc1\n\t"
          "global_load_dwordx4 %14, %19, off offset:2048 sc0 sc1\n\t"
          "global_load_dwordx4 %15, %19, off offset:3072 sc0 sc1\n\t"
          "s_waitcnt vmcnt(0)"
          : "=&v"(ha[0]), "=&v"(ha[1]), "=&v"(ha[2]), "=&v"(ha[3]),
            "=&v"(ha[4]), "=&v"(ha[5]), "=&v"(ha[6]), "=&v"(ha[7]),
            "=&v"(ha[8]), "=&v"(ha[9]), "=&v"(ha[10]), "=&v"(ha[11]),
            "=&v"(ha[12]), "=&v"(ha[13]), "=&v"(ha[14]), "=&v"(ha[15])
          : "v"(b0), "v"(b4), "v"(b8), "v"(b12));
    }

    // ---- MFMA: 4 chains of 8 (k-split), B from registers ----
    f32x4 a0a = xw0, a1a = xw1;
    f32x4 a0b = {0.f, 0.f, 0.f, 0.f}, a1b = {0.f, 0.f, 0.f, 0.f};
#pragma unroll
    for (int ks = 0; ks < 8; ++ks) {
      bf16x8 aA = __builtin_bit_cast(bf16x8, ha[ks]);
      bf16x8 aB = __builtin_bit_cast(bf16x8, ha[8 + ks]);
      a0a = __builtin_amdgcn_mfma_f32_16x16x32_bf16(aA, bfr[0][ks], a0a, 0, 0, 0);
      a1a = __builtin_amdgcn_mfma_f32_16x16x32_bf16(aA, bfr[1][ks], a1a, 0, 0, 0);
      a0b = __builtin_amdgcn_mfma_f32_16x16x32_bf16(aB, bfr[0][8 + ks], a0b, 0, 0, 0);
      a1b = __builtin_amdgcn_mfma_f32_16x16x32_bf16(aB, bfr[1][8 + ks], a1b, 0, 0, 0);
    }
    f32x4 acc0 = a0a + a0b, acc1 = a1a + a1b;

    // ---- gate exchange via shfl_xor(8): lanes n<8 hold F,G; n>=8 hold I,O ----
    float t00 = __shfl_xor(hi ? acc0[0] : acc0[2], 8, 64);
    float t01 = __shfl_xor(hi ? acc0[1] : acc0[3], 8, 64);
    float t20 = __shfl_xor(hi ? acc1[0] : acc1[2], 8, 64);
    float t21 = __shfl_xor(hi ? acc1[1] : acc1[3], 8, 64);

    float hnew_s[2], cnew_s[2];
    u32 h16_s[2];
#pragma unroll
    for (int it = 0; it < 2; ++it) {
      int r = r0 + it;
      float tx0 = it ? t01 : t00;
      float tx2 = it ? t21 : t20;
      float zf = hi ? tx0 : acc0[it];
      float zi = hi ? acc0[r] : tx0;
      float zg = hi ? tx2 : acc1[it];
      float zo = hi ? acc1[r] : tx2;
      float fg = sigf(zf), ig = sigf(zi), gg = tanh_fast(zg), og = sigf(zo);
      float cnew = fg * creg[it] + ig * gg;
      float hnew = og * tanh_fast(cnew);
      creg[it] = cnew;
      hnew_s[it] = hnew; cnew_s[it] = cnew;
      h16_s[it] = (u32)f2bf(hnew);
    }

    // ---- publish: pair jj with jj^1 -> full-dword coherent stores (even-jj lanes) ----
    {
      u32 part0 = (u32)__shfl_xor((int)h16_s[0], 1, 64);
      u32 part1 = (u32)__shfl_xor((int)h16_s[1], 1, 64);
      if ((jj & 1) == 0) {
        u32 p0 = h16_s[0] | (part0 << 16);
        u32 p1 = h16_s[1] | (part1 << 16);
        size_t ci0 = ((((size_t)v * 16 + (w >> 2)) * 4 + (w & 3)) * 16 + (q * 4 + r0));
        char* dst = hnxt + ci0 * 16 + jj * 2;
        asm volatile(
            "global_store_dword %0, %1, off sc0 sc1\n\t"
            "global_store_dword %0, %2, off offset:16 sc0 sc1"
            :: "v"(dst), "v"(p0), "v"(p1));
      }
    }
    // drain publish stores; memory clobber keeps shadow ops below this point
    asm volatile("s_waitcnt vmcnt(0)" ::: "memory");
    if (lane == 0) {
      u32 tag = (u32)(t + 1);
      u32* fdst = flags + (w * 4 + v);
      asm volatile("global_store_dword %0, %1, off sc0 sc1" :: "v"(fdst), "v"(tag));
    }

    // ---- shadow work: XW(t+1) prefetch + out stores (drain during next poll) ----
    {
      int tn = (t + 1 < T_STEPS) ? t + 1 : t;
      size_t b0 = ((((size_t)tn * 4 + v) * 64 + w) * 2 + 0) * 64 + lane;
      if (xwf32) {
        xw0 = ((const f32x4*)xwp)[b0];
        xw1 = ((const f32x4*)xwp)[b0 + 64];
      } else {
        ushort4 a0 = ((const ushort4*)xwp)[b0];
        ushort4 a1 = ((const ushort4*)xwp)[b0 + 64];
        xw0[0] = bf2f(a0.x); xw0[1] = bf2f(a0.y); xw0[2] = bf2f(a0.z); xw0[3] = bf2f(a0.w);
        xw1[0] = bf2f(a1.x); xw1[1] = bf2f(a1.y); xw1[2] = bf2f(a1.z); xw1[3] = bf2f(a1.w);
      }
    }
#pragma unroll
    for (int it = 0; it < 2; ++it) {
      int b = v * 16 + q * 4 + r0 + it;
      size_t oi = ((size_t)t * 64 + b) * 512 + w * 8 + jj;
      if (mode) ((u16*)out)[oi] = (u16)h16_s[it]; else ((float*)out)[oi] = hnew_s[it];
      if (t == T_STEPS - 1) {
        size_t hx = NOUT_H + (size_t)b * 512 + w * 8 + jj;
        if (mode) { ((u16*)out)[hx] = (u16)h16_s[it]; ((u16*)out)[hx + 32768] = f2bf(cnew_s[it]); }
        else      { ((float*)out)[hx] = hnew_s[it]; ((float*)out)[hx + 32768] = cnew_s[it]; }
      }
    }
  }
}

extern "C" void kernel_launch(void* const* d_in, const int* in_sizes, int n_in,
                              void* d_out, int out_size, void* d_ws, size_t ws_size,
                              hipStream_t stream) {
  const void* X = d_in[0];
  u32* ws = (u32*)d_ws;
  int xwf32 = (ws_size >= (size_t)(WS_XW + 268435456ull + 1024ull)) ? 1 : 0;

  k_detect<<<1, 256, 0, stream>>>((const u32*)X, ws);
  k_convx<<<16384, 256, 0, stream>>>(ws, X, (u16*)((char*)d_ws + WS_XC));
  k_prepw<<<1024, 256, 0, stream>>>(ws, d_in[1], d_in[3], d_in[5], d_in[7],
                                    d_in[2], d_in[4], d_in[6], d_in[8]);
  k_xw<<<8192, 256, 0, stream>>>(ws, X, xwf32);
  k_rec<<<64, 256, 0, stream>>>(ws, d_out, xwf32);
}